// Round 1
// baseline (505.233 us; speedup 1.0000x reference)
//
#include <hip/hip_runtime.h>
#include <cstdint>
#include <cstddef>

// ---------------------------------------------------------------------------
// MultiHeadAttn: B=4, T=2048, D=1024, H=16, HD=64
//   qp = q@Wq^T+bq ; kp,vp likewise ; per-head flash attention (scale 1/32,
//   key mask -> -65504) ; out = attn@Wo^T+bo (fp32)
// Pipeline: cvt(fp32->bf16) -> 3x GEMM(bf16, m97 structure) -> flash attn
//           -> GEMM -> fp32 out
// ---------------------------------------------------------------------------

typedef __attribute__((ext_vector_type(8))) short bf16x8;
typedef __attribute__((ext_vector_type(4))) float f32x4;

#define MFMA16(a, b, c) __builtin_amdgcn_mfma_f32_16x16x32_bf16((a), (b), (c), 0, 0, 0)

__device__ __forceinline__ void gload_lds16(const void* g, void* l) {
  __builtin_amdgcn_global_load_lds((const __attribute__((address_space(1))) void*)g,
                                   (__attribute__((address_space(3))) void*)l,
                                   16, 0, 0);
}

__device__ __forceinline__ unsigned short f2bf(float f) {
  union { float f; unsigned u; } x; x.f = f;
  unsigned r = x.u + 0x7fffu + ((x.u >> 16) & 1u);   // RTNE
  return (unsigned short)(r >> 16);
}

// ---------------------------- fp32 -> bf16 convert -------------------------
struct CvtArgs {
  const float* src[7];
  unsigned short* dst[7];
  int n4[7];
};

__global__ __launch_bounds__(256) void cvt_kernel(CvtArgs a) {
  const int t = blockIdx.y;
  const int i = blockIdx.x * 256 + threadIdx.x;
  if (i >= a.n4[t]) return;
  const float4 v = ((const float4*)a.src[t])[i];
  ushort4 o;
  o.x = f2bf(v.x); o.y = f2bf(v.y); o.z = f2bf(v.z); o.w = f2bf(v.w);
  ((ushort4*)a.dst[t])[i] = o;
}

// ------------------------------- GEMM (NT) ---------------------------------
// out[m][n] = sum_k A[m][k]*W[n][k] + bias[n];  M=8192, N=K=1024
// 128x128 tile, BK=32, 256 thr = 4 waves (2x2), each wave 64x64 (4x4 frags)
template <int F32OUT>
__global__ __launch_bounds__(256, 2) void gemm_nt(
    const unsigned short* __restrict__ A,   // [M][1024] bf16 bits
    const unsigned short* __restrict__ W,   // [1024][1024] bf16 bits
    const float* __restrict__ bias,         // [1024]
    void* __restrict__ outp)
{
  constexpr int K = 1024, N = 1024;
  __shared__ unsigned short As[128 * 32];
  __shared__ unsigned short Bs[128 * 32];

  const int tid = threadIdx.x;
  const int w = tid >> 6, l = tid & 63;
  const int m0 = blockIdx.x * 128, n0 = blockIdx.y * 128;
  const int wm = (w >> 1) * 64, wn = (w & 1) * 64;
  const int fr = l & 15, kg = (l >> 4) * 8;

  // staging: wave w, round r: lds elems base (w*2+r)*512, lane covers +l*8..+8
  const int srow = w * 32 + (l >> 2);
  const int sk = (l & 3) * 8;
  const unsigned short* Ag0 = A + (size_t)(m0 + srow) * K + sk;
  const unsigned short* Ag1 = Ag0 + (size_t)16 * K;
  const unsigned short* Wg0 = W + (size_t)(n0 + srow) * K + sk;
  const unsigned short* Wg1 = Wg0 + (size_t)16 * K;
  unsigned short* Asl0 = As + w * 1024;
  unsigned short* Asl1 = As + w * 1024 + 512;
  unsigned short* Bsl0 = Bs + w * 1024;
  unsigned short* Bsl1 = Bs + w * 1024 + 512;

  f32x4 acc[4][4] = {};

  for (int kt = 0; kt < K; kt += 32) {
    gload_lds16(Ag0 + kt, Asl0);
    gload_lds16(Ag1 + kt, Asl1);
    gload_lds16(Wg0 + kt, Bsl0);
    gload_lds16(Wg1 + kt, Bsl1);
    __syncthreads();

    bf16x8 af[4], bfv[4];
#pragma unroll
    for (int mt = 0; mt < 4; ++mt)
      af[mt] = *(const bf16x8*)(As + (wm + mt * 16 + fr) * 32 + kg);
#pragma unroll
    for (int nt = 0; nt < 4; ++nt)
      bfv[nt] = *(const bf16x8*)(Bs + (wn + nt * 16 + fr) * 32 + kg);
#pragma unroll
    for (int mt = 0; mt < 4; ++mt)
#pragma unroll
      for (int nt = 0; nt < 4; ++nt)
        acc[mt][nt] = MFMA16(af[mt], bfv[nt], acc[mt][nt]);
    __syncthreads();
  }

  const int rg = (l >> 4) * 4;
  float bv[4];
#pragma unroll
  for (int nt = 0; nt < 4; ++nt) bv[nt] = bias[n0 + wn + nt * 16 + fr];

#pragma unroll
  for (int mt = 0; mt < 4; ++mt) {
#pragma unroll
    for (int nt = 0; nt < 4; ++nt) {
      const int col = n0 + wn + nt * 16 + fr;
#pragma unroll
      for (int r = 0; r < 4; ++r) {
        const size_t row = (size_t)(m0 + wm + mt * 16 + rg + r);
        const float vv = acc[mt][nt][r] + bv[nt];
        if (F32OUT) ((float*)outp)[row * N + col] = vv;
        else        ((unsigned short*)outp)[row * N + col] = f2bf(vv);
      }
    }
  }
}

// ----------------------------- flash attention -----------------------------
// grid: (T/64=32, H=16, B=4); 256 thr = 4 waves; wave w handles 16 q-rows.
__global__ __launch_bounds__(256, 2) void attn_kernel(
    const unsigned short* __restrict__ QP,  // [B*T][1024] bf16
    const unsigned short* __restrict__ KP,
    const unsigned short* __restrict__ VP,
    const int* __restrict__ mask,           // [B][T]
    unsigned short* __restrict__ O)         // [B*T][1024] bf16
{
  __shared__ unsigned short Kls[64 * 72];       // K tile (also Q staging), padded
  __shared__ unsigned short VTls[64 * 72];      // V^T tile [d][kv], padded
  __shared__ unsigned short Pls[4][16 * 72];    // per-wave P tile

  const int qt = blockIdx.x, h = blockIdx.y, b = blockIdx.z;
  const int tid = threadIdx.x, w = tid >> 6, l = tid & 63;
  const int fr = l & 15, kg = (l >> 4) * 8;
  const size_t brow = (size_t)b * 2048;
  const int hcol = h * 64;

  // ---- stage Q tile (64 rows x 64 cols) into Kls ----
  {
    const int row = tid >> 3, c = (tid & 7) * 8;
    const unsigned short* src = QP + (brow + qt * 64 + row) * 1024 + hcol + c;
    *(uint4*)(&Kls[row * 72 + c]) = *(const uint4*)src;
    *(uint4*)(&Kls[(row + 32) * 72 + c]) = *(const uint4*)(src + 32 * 1024);
  }
  __syncthreads();
  bf16x8 qf[2];
  qf[0] = *(const bf16x8*)(&Kls[(w * 16 + fr) * 72 + kg]);
  qf[1] = *(const bf16x8*)(&Kls[(w * 16 + fr) * 72 + 32 + kg]);

  float m_run[4] = {-1e30f, -1e30f, -1e30f, -1e30f};
  float l_run[4] = {0.f, 0.f, 0.f, 0.f};
  f32x4 o[4] = {};
  const float scale = 0.03125f;  // 1/sqrt(1024)
  const int* mrow = mask + b * 2048;

  for (int kv0 = 0; kv0 < 2048; kv0 += 64) {
    __syncthreads();  // previous iter's LDS reads (and Q-frag loads) done
    // ---- stage K tile ----
    {
      const int row = tid >> 3, c = (tid & 7) * 8;
      const unsigned short* src = KP + (brow + kv0 + row) * 1024 + hcol + c;
      *(uint4*)(&Kls[row * 72 + c]) = *(const uint4*)src;
      *(uint4*)(&Kls[(row + 32) * 72 + c]) = *(const uint4*)(src + 32 * 1024);
    }
    // ---- stage V^T tile (4x4 in-register micro-transpose) ----
    {
      const int tkv = (tid & 15) * 4, td = (tid >> 4) * 4;
      const unsigned short* vs = VP + (brow + kv0 + tkv) * 1024 + hcol + td;
      ushort4 r0 = *(const ushort4*)(vs);
      ushort4 r1 = *(const ushort4*)(vs + 1024);
      ushort4 r2 = *(const ushort4*)(vs + 2048);
      ushort4 r3 = *(const ushort4*)(vs + 3072);
      ushort4 c0 = {r0.x, r1.x, r2.x, r3.x};
      ushort4 c1 = {r0.y, r1.y, r2.y, r3.y};
      ushort4 c2 = {r0.z, r1.z, r2.z, r3.z};
      ushort4 c3 = {r0.w, r1.w, r2.w, r3.w};
      *(ushort4*)(&VTls[(td + 0) * 72 + tkv]) = c0;
      *(ushort4*)(&VTls[(td + 1) * 72 + tkv]) = c1;
      *(ushort4*)(&VTls[(td + 2) * 72 + tkv]) = c2;
      *(ushort4*)(&VTls[(td + 3) * 72 + tkv]) = c3;
    }
    __syncthreads();

    // ---- S = Q K^T : wave's 16 rows x 64 cols ----
    f32x4 s[4] = {};
#pragma unroll
    for (int nt = 0; nt < 4; ++nt) {
      bf16x8 kf0 = *(const bf16x8*)(&Kls[(nt * 16 + fr) * 72 + kg]);
      bf16x8 kf1 = *(const bf16x8*)(&Kls[(nt * 16 + fr) * 72 + 32 + kg]);
      s[nt] = MFMA16(qf[0], kf0, s[nt]);
      s[nt] = MFMA16(qf[1], kf1, s[nt]);
    }

    // ---- online softmax (C-layout: row=(l>>4)*4+r, col=nt*16+fr) ----
    float sv[4][4];
    int msk[4];
#pragma unroll
    for (int nt = 0; nt < 4; ++nt) msk[nt] = mrow[kv0 + nt * 16 + fr];
#pragma unroll
    for (int nt = 0; nt < 4; ++nt)
#pragma unroll
      for (int r = 0; r < 4; ++r)
        sv[nt][r] = msk[nt] ? s[nt][r] * scale : -65504.0f;

    float rmax[4], alpha[4], psum[4];
#pragma unroll
    for (int r = 0; r < 4; ++r)
      rmax[r] = fmaxf(fmaxf(sv[0][r], sv[1][r]), fmaxf(sv[2][r], sv[3][r]));
#pragma unroll
    for (int mb = 1; mb <= 8; mb <<= 1)
#pragma unroll
      for (int r = 0; r < 4; ++r)
        rmax[r] = fmaxf(rmax[r], __shfl_xor(rmax[r], mb));
#pragma unroll
    for (int r = 0; r < 4; ++r) {
      const float mn = fmaxf(m_run[r], rmax[r]);
      alpha[r] = __expf(m_run[r] - mn);
      m_run[r] = mn;
      psum[r] = 0.f;
    }
#pragma unroll
    for (int nt = 0; nt < 4; ++nt)
#pragma unroll
      for (int r = 0; r < 4; ++r) {
        const float p = __expf(sv[nt][r] - m_run[r]);
        sv[nt][r] = p;
        psum[r] += p;
      }
#pragma unroll
    for (int mb = 1; mb <= 8; mb <<= 1)
#pragma unroll
      for (int r = 0; r < 4; ++r)
        psum[r] += __shfl_xor(psum[r], mb);
#pragma unroll
    for (int r = 0; r < 4; ++r)
      l_run[r] = l_run[r] * alpha[r] + psum[r];
#pragma unroll
    for (int dt = 0; dt < 4; ++dt)
#pragma unroll
      for (int r = 0; r < 4; ++r)
        o[dt][r] *= alpha[r];

    // ---- P -> wave-private LDS (re-layout C-frag -> A-frag) ----
    const int rg = (l >> 4) * 4;
#pragma unroll
    for (int nt = 0; nt < 4; ++nt)
#pragma unroll
      for (int r = 0; r < 4; ++r)
        Pls[w][(rg + r) * 72 + nt * 16 + fr] = f2bf(sv[nt][r]);

    __syncthreads();  // conservative this round; P is wave-private

    // ---- O += P V ----
#pragma unroll
    for (int ks = 0; ks < 2; ++ks) {
      bf16x8 pa = *(const bf16x8*)(&Pls[w][fr * 72 + ks * 32 + kg]);
#pragma unroll
      for (int dt = 0; dt < 4; ++dt) {
        bf16x8 vb = *(const bf16x8*)(&VTls[(dt * 16 + fr) * 72 + ks * 32 + kg]);
        o[dt] = MFMA16(pa, vb, o[dt]);
      }
    }
  }

  // ---- epilogue: O/l -> bf16 ----
  const int rg = (l >> 4) * 4;
  float inv[4];
#pragma unroll
  for (int r = 0; r < 4; ++r) inv[r] = 1.0f / l_run[r];
#pragma unroll
  for (int dt = 0; dt < 4; ++dt)
#pragma unroll
    for (int r = 0; r < 4; ++r) {
      const size_t row = brow + (size_t)(qt * 64 + w * 16 + rg + r);
      const int col = hcol + dt * 16 + fr;
      O[row * 1024 + col] = f2bf(o[dt][r] * inv[r]);
    }
}

// ------------------------------ launch -------------------------------------
extern "C" void kernel_launch(void* const* d_in, const int* in_sizes, int n_in,
                              void* d_out, int out_size, void* d_ws, size_t ws_size,
                              hipStream_t stream) {
  const float* q  = (const float*)d_in[0];
  const float* k  = (const float*)d_in[1];
  const float* v  = (const float*)d_in[2];
  const int*  msk = (const int*)d_in[3];
  const float* Wq = (const float*)d_in[4];
  const float* bq = (const float*)d_in[5];
  const float* Wk = (const float*)d_in[6];
  const float* bk = (const float*)d_in[7];
  const float* Wv = (const float*)d_in[8];
  const float* bv = (const float*)d_in[9];
  const float* Wo = (const float*)d_in[10];
  const float* bo = (const float*)d_in[11];

  char* ws = (char*)d_ws;
  const size_t SZ_BT = (size_t)8192 * 1024 * 2;  // 16 MiB (bf16 B*T x 1024)
  const size_t SZ_W  = (size_t)1024 * 1024 * 2;  // 2 MiB
  unsigned short* qb  = (unsigned short*)(ws);
  unsigned short* kb  = (unsigned short*)(ws + SZ_BT);
  unsigned short* vb  = (unsigned short*)(ws + 2 * SZ_BT);
  unsigned short* Wqb = (unsigned short*)(ws + 3 * SZ_BT);
  unsigned short* Wkb = (unsigned short*)(ws + 3 * SZ_BT + SZ_W);
  unsigned short* Wvb = (unsigned short*)(ws + 3 * SZ_BT + 2 * SZ_W);
  unsigned short* Wob = (unsigned short*)(ws + 3 * SZ_BT + 3 * SZ_W);
  unsigned short* QPp = (unsigned short*)(ws + 3 * SZ_BT + 4 * SZ_W);
  unsigned short* KPp = (unsigned short*)(ws + 4 * SZ_BT + 4 * SZ_W);
  unsigned short* VPp = (unsigned short*)(ws + 5 * SZ_BT + 4 * SZ_W);
  unsigned short* AOp = (unsigned short*)(ws + 6 * SZ_BT + 4 * SZ_W);
  // total ws use: 6*16MiB + 4*2MiB + 16MiB = 120 MiB

  CvtArgs ca;
  ca.src[0] = q;  ca.dst[0] = qb;  ca.n4[0] = 8192 * 1024 / 4;
  ca.src[1] = k;  ca.dst[1] = kb;  ca.n4[1] = 8192 * 1024 / 4;
  ca.src[2] = v;  ca.dst[2] = vb;  ca.n4[2] = 8192 * 1024 / 4;
  ca.src[3] = Wq; ca.dst[3] = Wqb; ca.n4[3] = 1024 * 1024 / 4;
  ca.src[4] = Wk; ca.dst[4] = Wkb; ca.n4[4] = 1024 * 1024 / 4;
  ca.src[5] = Wv; ca.dst[5] = Wvb; ca.n4[5] = 1024 * 1024 / 4;
  ca.src[6] = Wo; ca.dst[6] = Wob; ca.n4[6] = 1024 * 1024 / 4;
  cvt_kernel<<<dim3(8192, 7), 256, 0, stream>>>(ca);

  const dim3 gg(64, 8);
  gemm_nt<0><<<gg, 256, 0, stream>>>(qb, Wqb, bq, QPp);
  gemm_nt<0><<<gg, 256, 0, stream>>>(kb, Wkb, bk, KPp);
  gemm_nt<0><<<gg, 256, 0, stream>>>(vb, Wvb, bv, VPp);

  attn_kernel<<<dim3(32, 16, 4), 256, 0, stream>>>(QPp, KPp, VPp, msk, AOp);

  gemm_nt<1><<<gg, 256, 0, stream>>>(AOp, Wob, bo, d_out);
}

// Round 2
// 430.088 us; speedup vs baseline: 1.1747x; 1.1747x over previous
//
#include <hip/hip_runtime.h>
#include <cstdint>
#include <cstddef>

// ---------------------------------------------------------------------------
// MultiHeadAttn: B=4, T=2048, D=1024, H=16, HD=64
// cvt(fp32->bf16) + maskf -> fused QKV GEMM (bf16) -> flash attn -> out GEMM
// ---------------------------------------------------------------------------

typedef __attribute__((ext_vector_type(8))) short bf16x8;
typedef __attribute__((ext_vector_type(4))) float f32x4;

#define MFMA16(a, b, c) __builtin_amdgcn_mfma_f32_16x16x32_bf16((a), (b), (c), 0, 0, 0)

__device__ __forceinline__ void gload_lds16(const void* g, void* l) {
  __builtin_amdgcn_global_load_lds((const __attribute__((address_space(1))) void*)g,
                                   (__attribute__((address_space(3))) void*)l,
                                   16, 0, 0);
}

__device__ __forceinline__ unsigned short f2bf(float f) {  // RTNE
  union { float f; unsigned u; } x; x.f = f;
  unsigned r = x.u + 0x7fffu + ((x.u >> 16) & 1u);
  return (unsigned short)(r >> 16);
}

__device__ __forceinline__ unsigned short f2bf_cvt(float f) {  // 1 VALU op
  unsigned r;
  asm("v_cvt_pk_bf16_f32 %0, %1, 0" : "=v"(r) : "v"(f));
  return (unsigned short)r;
}

// ---- DPP 16-lane-row reductions (VALU pipe, no LDS) ----
template <int C>
__device__ __forceinline__ float dppf(float x) {
  return __builtin_bit_cast(float, __builtin_amdgcn_update_dpp(
      0, __builtin_bit_cast(int, x), C, 0xF, 0xF, true));
}
__device__ __forceinline__ float rowmax16(float x) {
  x = fmaxf(x, dppf<0x128>(x));  // row_ror:8
  x = fmaxf(x, dppf<0x124>(x));  // row_ror:4
  x = fmaxf(x, dppf<0x4E>(x));   // quad_perm xor2
  x = fmaxf(x, dppf<0xB1>(x));   // quad_perm xor1
  return x;
}
__device__ __forceinline__ float rowsum16(float x) {
  x += dppf<0x128>(x);
  x += dppf<0x124>(x);
  x += dppf<0x4E>(x);
  x += dppf<0xB1>(x);
  return x;
}

// ---------------------------- fp32 -> bf16 convert -------------------------
struct CvtArgs {
  const float* src[7];
  unsigned short* dst[7];
};

// t<3: 8192 blocks each (2M float4); t>=3: 1024 blocks each (256K float4)
__global__ __launch_bounds__(256) void cvt_kernel(CvtArgs a) {
  const int bid = blockIdx.x;
  int t, i;
  if (bid < 24576) { t = bid >> 13; i = ((bid & 8191) << 8) + threadIdx.x; }
  else { const int r = bid - 24576; t = 3 + (r >> 10); i = ((r & 1023) << 8) + threadIdx.x; }
  const float4 v = ((const float4*)a.src[t])[i];
  ushort4 o;
  o.x = f2bf(v.x); o.y = f2bf(v.y); o.z = f2bf(v.z); o.w = f2bf(v.w);
  ((ushort4*)a.dst[t])[i] = o;
}

__global__ __launch_bounds__(256) void mask_kernel(const int* __restrict__ m,
                                                   float* __restrict__ mf) {
  const int i = blockIdx.x * 256 + threadIdx.x;  // 8192 total
  mf[i] = m[i] ? 0.0f : -65504.0f;
}

// ------------------------------- GEMM (NT) ---------------------------------
// out[m][n] = sum_k A[m][k]*W[n][k] + bias[n];  M=8192, N=K=1024
// 128x128 tile, BK=32, 256 thr = 4 waves (2x2), wave = 64x64 (4x4 frags)
struct GemmB {
  const unsigned short* A[3];
  const unsigned short* W[3];
  const float* bias[3];
  unsigned short* out[3];
};

template <int NB, int F32OUT>
__global__ __launch_bounds__(256, 2) void gemm_nt(GemmB gb, float* fout) {
  constexpr int K = 1024, N = 1024;
  __shared__ unsigned short As[128 * 32];
  __shared__ unsigned short Bs[128 * 32];

  // XCD-bijective swizzle over the flat grid (nwg % 8 == 0)
  const int nwg = NB * 512;
  const int wg = blockIdx.x;
  const int swz = (wg & 7) * (nwg >> 3) + (wg >> 3);
  const int which = swz >> 9;            // 0..NB-1
  const int rr = swz & 511;
  const int m0 = (rr & 63) * 128, n0 = (rr >> 6) * 128;

  const unsigned short* __restrict__ A = gb.A[which];
  const unsigned short* __restrict__ W = gb.W[which];
  const float* __restrict__ bias = gb.bias[which];

  const int tid = threadIdx.x;
  const int w = tid >> 6, l = tid & 63;
  const int wm = (w >> 1) * 64, wn = (w & 1) * 64;
  const int fr = l & 15, kg = (l >> 4) * 8;

  const int srow = w * 32 + (l >> 2);
  const int sk = (l & 3) * 8;
  const unsigned short* Ag0 = A + (size_t)(m0 + srow) * K + sk;
  const unsigned short* Ag1 = Ag0 + (size_t)16 * K;
  const unsigned short* Wg0 = W + (size_t)(n0 + srow) * K + sk;
  const unsigned short* Wg1 = Wg0 + (size_t)16 * K;
  unsigned short* Asl0 = As + w * 1024;
  unsigned short* Asl1 = As + w * 1024 + 512;
  unsigned short* Bsl0 = Bs + w * 1024;
  unsigned short* Bsl1 = Bs + w * 1024 + 512;

  f32x4 acc[4][4] = {};

  for (int kt = 0; kt < K; kt += 32) {
    gload_lds16(Ag0 + kt, Asl0);
    gload_lds16(Ag1 + kt, Asl1);
    gload_lds16(Wg0 + kt, Bsl0);
    gload_lds16(Wg1 + kt, Bsl1);
    __syncthreads();

    bf16x8 af[4], bfv[4];
#pragma unroll
    for (int mt = 0; mt < 4; ++mt)
      af[mt] = *(const bf16x8*)(As + (wm + mt * 16 + fr) * 32 + kg);
#pragma unroll
    for (int nt = 0; nt < 4; ++nt)
      bfv[nt] = *(const bf16x8*)(Bs + (wn + nt * 16 + fr) * 32 + kg);
#pragma unroll
    for (int mt = 0; mt < 4; ++mt)
#pragma unroll
      for (int nt = 0; nt < 4; ++nt)
        acc[mt][nt] = MFMA16(af[mt], bfv[nt], acc[mt][nt]);
    __syncthreads();
  }

  const int rg = (l >> 4) * 4;
  float bv[4];
#pragma unroll
  for (int nt = 0; nt < 4; ++nt) bv[nt] = bias[n0 + wn + nt * 16 + fr];

#pragma unroll
  for (int mt = 0; mt < 4; ++mt) {
#pragma unroll
    for (int nt = 0; nt < 4; ++nt) {
      const int col = n0 + wn + nt * 16 + fr;
#pragma unroll
      for (int r = 0; r < 4; ++r) {
        const size_t row = (size_t)(m0 + wm + mt * 16 + rg + r);
        const float vv = acc[mt][nt][r] + bv[nt];
        if (F32OUT) fout[row * N + col] = vv;
        else        gb.out[which][row * N + col] = f2bf(vv);
      }
    }
  }
}

// ----------------------------- flash attention -----------------------------
// grid: 1024 blocks (16 qtiles x 16 h x 4 b), 256 thr = 4 waves,
// wave owns 32 q-rows; KVBLK=64.
__global__ __launch_bounds__(256, 3) void attn_kernel(
    const unsigned short* __restrict__ QP,  // [B*T][1024] bf16
    const unsigned short* __restrict__ KP,
    const unsigned short* __restrict__ VP,
    const float* __restrict__ maskf,        // [B][T] additive (0 / -65504)
    unsigned short* __restrict__ O)         // [B*T][1024] bf16
{
  __shared__ unsigned short Kls[64 * 72];        // K tile, padded
  __shared__ unsigned short VTls[64 * 72];       // V^T tile [d][kv], padded
  __shared__ unsigned short Pls[4][32 * 72];     // per-wave P tile

  const int wg = blockIdx.x;
  const int swz = (wg & 7) * 128 + (wg >> 3);    // XCD swizzle, 1024 = 8*128
  const int qt = swz & 15, h = (swz >> 4) & 15, b = swz >> 8;

  const int tid = threadIdx.x, w = tid >> 6, l = tid & 63;
  const int fr = l & 15, kg = (l >> 4) * 8, rg = (l >> 4) * 4;
  const size_t brow = (size_t)b * 2048;
  const int hcol = h * 64;
  const int q0 = qt * 128 + w * 32;              // block-global first q-row of wave

  // ---- Q fragments straight from global ----
  bf16x8 qf[2][2];
  {
    const unsigned short* qb = QP + (brow + q0 + fr) * 1024 + hcol;
    qf[0][0] = *(const bf16x8*)(qb + kg);
    qf[0][1] = *(const bf16x8*)(qb + 32 + kg);
    qf[1][0] = *(const bf16x8*)(qb + 16 * 1024 + kg);
    qf[1][1] = *(const bf16x8*)(qb + 16 * 1024 + 32 + kg);
  }

  float m_run[2][4], l_run[2][4];
  f32x4 o[2][4] = {};
#pragma unroll
  for (int mt = 0; mt < 2; ++mt)
#pragma unroll
    for (int r = 0; r < 4; ++r) { m_run[mt][r] = -3e38f; l_run[mt][r] = 0.f; }

  const float scale = 0.03125f;  // 1/sqrt(1024)
  const float* mrow = maskf + b * 2048;

  const int krow = tid >> 3, kc = (tid & 7) * 8;
  const unsigned short* Ksrc = KP + (brow + krow) * 1024 + hcol + kc;
  const int tkv = (tid & 15) * 4, td = (tid >> 4) * 4;
  const unsigned short* Vsrc = VP + (brow + tkv) * 1024 + hcol + td;

  for (int kv0 = 0; kv0 < 2048; kv0 += 64) {
    __syncthreads();  // prior iter's K/V reads complete
    // ---- stage K tile (64x64) ----
    {
      const unsigned short* src = Ksrc + (size_t)kv0 * 1024;
      *(uint4*)(&Kls[krow * 72 + kc]) = *(const uint4*)src;
      *(uint4*)(&Kls[(krow + 32) * 72 + kc]) = *(const uint4*)(src + 32 * 1024);
    }
    // ---- stage V^T tile (4x4 micro-transpose) ----
    {
      const unsigned short* vs = Vsrc + (size_t)kv0 * 1024;
      ushort4 r0 = *(const ushort4*)(vs);
      ushort4 r1 = *(const ushort4*)(vs + 1024);
      ushort4 r2 = *(const ushort4*)(vs + 2048);
      ushort4 r3 = *(const ushort4*)(vs + 3072);
      ushort4 c0 = {r0.x, r1.x, r2.x, r3.x};
      ushort4 c1 = {r0.y, r1.y, r2.y, r3.y};
      ushort4 c2 = {r0.z, r1.z, r2.z, r3.z};
      ushort4 c3 = {r0.w, r1.w, r2.w, r3.w};
      *(ushort4*)(&VTls[(td + 0) * 72 + tkv]) = c0;
      *(ushort4*)(&VTls[(td + 1) * 72 + tkv]) = c1;
      *(ushort4*)(&VTls[(td + 2) * 72 + tkv]) = c2;
      *(ushort4*)(&VTls[(td + 3) * 72 + tkv]) = c3;
    }
    __syncthreads();

    // ---- S = Q K^T : 32 rows x 64 cols per wave ----
    f32x4 s[2][4] = {};
#pragma unroll
    for (int nt = 0; nt < 4; ++nt) {
      bf16x8 kf0 = *(const bf16x8*)(&Kls[(nt * 16 + fr) * 72 + kg]);
      bf16x8 kf1 = *(const bf16x8*)(&Kls[(nt * 16 + fr) * 72 + 32 + kg]);
      s[0][nt] = MFMA16(qf[0][0], kf0, s[0][nt]);
      s[0][nt] = MFMA16(qf[0][1], kf1, s[0][nt]);
      s[1][nt] = MFMA16(qf[1][0], kf0, s[1][nt]);
      s[1][nt] = MFMA16(qf[1][1], kf1, s[1][nt]);
    }

    // ---- softmax (additive mask folded into one FMA) ----
    float ma[4];
#pragma unroll
    for (int nt = 0; nt < 4; ++nt) ma[nt] = mrow[kv0 + nt * 16 + fr];

    float sv[2][4][4];
#pragma unroll
    for (int mt = 0; mt < 2; ++mt)
#pragma unroll
      for (int nt = 0; nt < 4; ++nt)
#pragma unroll
        for (int r = 0; r < 4; ++r)
          sv[mt][nt][r] = fmaf(s[mt][nt][r], scale, ma[nt]);

    float tmax[2][4];
#pragma unroll
    for (int mt = 0; mt < 2; ++mt)
#pragma unroll
      for (int r = 0; r < 4; ++r) {
        float t = fmaxf(fmaxf(sv[mt][0][r], sv[mt][1][r]),
                        fmaxf(sv[mt][2][r], sv[mt][3][r]));
        tmax[mt][r] = rowmax16(t);
      }

    // defer-max: rescale only when the running max grows by > 8
    float dmax = -3e38f;
#pragma unroll
    for (int mt = 0; mt < 2; ++mt)
#pragma unroll
      for (int r = 0; r < 4; ++r)
        dmax = fmaxf(dmax, tmax[mt][r] - m_run[mt][r]);
    if (!__all(dmax <= 8.0f)) {
#pragma unroll
      for (int mt = 0; mt < 2; ++mt)
#pragma unroll
        for (int r = 0; r < 4; ++r) {
          const float mn = fmaxf(m_run[mt][r], tmax[mt][r]);
          const float alpha = __expf(m_run[mt][r] - mn);
          m_run[mt][r] = mn;
          l_run[mt][r] *= alpha;
#pragma unroll
          for (int dt = 0; dt < 4; ++dt) o[mt][dt][r] *= alpha;
        }
    }

    float psum[2][4] = {};
#pragma unroll
    for (int mt = 0; mt < 2; ++mt)
#pragma unroll
      for (int nt = 0; nt < 4; ++nt)
#pragma unroll
        for (int r = 0; r < 4; ++r) {
          const float p = __expf(sv[mt][nt][r] - m_run[mt][r]);
          psum[mt][r] += p;
          Pls[w][(mt * 16 + rg + r) * 72 + nt * 16 + fr] = f2bf_cvt(p);
        }
#pragma unroll
    for (int mt = 0; mt < 2; ++mt)
#pragma unroll
      for (int r = 0; r < 4; ++r)
        l_run[mt][r] += rowsum16(psum[mt][r]);

    // ---- O += P V (P is wave-private; DS in-order within wave) ----
    bf16x8 pa[2][2];
#pragma unroll
    for (int mt = 0; mt < 2; ++mt)
#pragma unroll
      for (int ks = 0; ks < 2; ++ks)
        pa[mt][ks] = *(const bf16x8*)(&Pls[w][(mt * 16 + fr) * 72 + ks * 32 + kg]);
#pragma unroll
    for (int dt = 0; dt < 4; ++dt) {
      bf16x8 vb0 = *(const bf16x8*)(&VTls[(dt * 16 + fr) * 72 + kg]);
      bf16x8 vb1 = *(const bf16x8*)(&VTls[(dt * 16 + fr) * 72 + 32 + kg]);
      o[0][dt] = MFMA16(pa[0][0], vb0, o[0][dt]);
      o[0][dt] = MFMA16(pa[0][1], vb1, o[0][dt]);
      o[1][dt] = MFMA16(pa[1][0], vb0, o[1][dt]);
      o[1][dt] = MFMA16(pa[1][1], vb1, o[1][dt]);
    }
  }

  // ---- epilogue ----
#pragma unroll
  for (int mt = 0; mt < 2; ++mt) {
    float inv[4];
#pragma unroll
    for (int r = 0; r < 4; ++r) inv[r] = 1.0f / l_run[mt][r];
#pragma unroll
    for (int dt = 0; dt < 4; ++dt)
#pragma unroll
      for (int r = 0; r < 4; ++r) {
        const size_t row = brow + (size_t)(q0 + mt * 16 + rg + r);
        O[row * 1024 + hcol + dt * 16 + fr] = f2bf(o[mt][dt][r] * inv[r]);
      }
  }
}

// ------------------------------ launch -------------------------------------
extern "C" void kernel_launch(void* const* d_in, const int* in_sizes, int n_in,
                              void* d_out, int out_size, void* d_ws, size_t ws_size,
                              hipStream_t stream) {
  const float* q  = (const float*)d_in[0];
  const float* k  = (const float*)d_in[1];
  const float* v  = (const float*)d_in[2];
  const int*  msk = (const int*)d_in[3];
  const float* Wq = (const float*)d_in[4];
  const float* bq = (const float*)d_in[5];
  const float* Wk = (const float*)d_in[6];
  const float* bk = (const float*)d_in[7];
  const float* Wv = (const float*)d_in[8];
  const float* bv = (const float*)d_in[9];
  const float* Wo = (const float*)d_in[10];
  const float* bo = (const float*)d_in[11];

  char* ws = (char*)d_ws;
  const size_t SZ_BT = (size_t)8192 * 1024 * 2;  // 16 MiB
  const size_t SZ_W  = (size_t)1024 * 1024 * 2;  // 2 MiB
  unsigned short* qb  = (unsigned short*)(ws);
  unsigned short* kb  = (unsigned short*)(ws + SZ_BT);
  unsigned short* vb  = (unsigned short*)(ws + 2 * SZ_BT);
  unsigned short* Wqb = (unsigned short*)(ws + 3 * SZ_BT);
  unsigned short* Wkb = (unsigned short*)(ws + 3 * SZ_BT + SZ_W);
  unsigned short* Wvb = (unsigned short*)(ws + 3 * SZ_BT + 2 * SZ_W);
  unsigned short* Wob = (unsigned short*)(ws + 3 * SZ_BT + 3 * SZ_W);
  unsigned short* QPp = (unsigned short*)(ws + 3 * SZ_BT + 4 * SZ_W);
  unsigned short* KPp = (unsigned short*)(ws + 4 * SZ_BT + 4 * SZ_W);
  unsigned short* VPp = (unsigned short*)(ws + 5 * SZ_BT + 4 * SZ_W);
  unsigned short* AOp = (unsigned short*)(ws + 6 * SZ_BT + 4 * SZ_W);
  float*          mkf = (float*)(ws + 7 * SZ_BT + 4 * SZ_W);
  // total ws use: 7*16MiB + 4*2MiB + 32KiB ≈ 120 MiB

  CvtArgs ca;
  ca.src[0] = q;  ca.dst[0] = qb;
  ca.src[1] = k;  ca.dst[1] = kb;
  ca.src[2] = v;  ca.dst[2] = vb;
  ca.src[3] = Wq; ca.dst[3] = Wqb;
  ca.src[4] = Wk; ca.dst[4] = Wkb;
  ca.src[5] = Wv; ca.dst[5] = Wvb;
  ca.src[6] = Wo; ca.dst[6] = Wob;
  cvt_kernel<<<dim3(28672), 256, 0, stream>>>(ca);
  mask_kernel<<<dim3(32), 256, 0, stream>>>(msk, mkf);

  GemmB g3;
  g3.A[0] = qb; g3.W[0] = Wqb; g3.bias[0] = bq; g3.out[0] = QPp;
  g3.A[1] = kb; g3.W[1] = Wkb; g3.bias[1] = bk; g3.out[1] = KPp;
  g3.A[2] = vb; g3.W[2] = Wvb; g3.bias[2] = bv; g3.out[2] = VPp;
  gemm_nt<3, 0><<<dim3(1536), 256, 0, stream>>>(g3, nullptr);

  attn_kernel<<<dim3(1024), 256, 0, stream>>>(QPp, KPp, VPp, mkf, AOp);

  GemmB g1;
  g1.A[0] = AOp; g1.W[0] = Wob; g1.bias[0] = bo; g1.out[0] = nullptr;
  gemm_nt<1, 1><<<dim3(512), 256, 0, stream>>>(g1, (float*)d_out);
}

// Round 3
// 404.933 us; speedup vs baseline: 1.2477x; 1.0621x over previous
//
#include <hip/hip_runtime.h>
#include <cstdint>
#include <cstddef>

// ---------------------------------------------------------------------------
// MultiHeadAttn: B=4, T=2048, D=1024, H=16, HD=64
// cvt(fp32->bf16) + maskf -> fused QKV GEMM (bf16) -> flash attn (swapped
// QK^T, in-register softmax, 32x32x16 MFMA) -> out GEMM (fp32)
// ---------------------------------------------------------------------------

typedef __attribute__((ext_vector_type(8))) short bf16x8;
typedef __attribute__((ext_vector_type(4))) short bf16x4;
typedef __attribute__((ext_vector_type(4))) float f32x4;
typedef __attribute__((ext_vector_type(16))) float f32x16;
typedef __attribute__((ext_vector_type(4))) unsigned uint4v;

#define MFMA16(a, b, c) __builtin_amdgcn_mfma_f32_16x16x32_bf16((a), (b), (c), 0, 0, 0)
#define MFMA32(a, b, c) __builtin_amdgcn_mfma_f32_32x32x16_bf16((a), (b), (c), 0, 0, 0)

__device__ __forceinline__ void gload_lds16(const void* g, void* l) {
  __builtin_amdgcn_global_load_lds((const __attribute__((address_space(1))) void*)g,
                                   (__attribute__((address_space(3))) void*)l,
                                   16, 0, 0);
}

__device__ __forceinline__ unsigned short f2bf(float f) {  // RTNE
  union { float f; unsigned u; } x; x.f = f;
  unsigned r = x.u + 0x7fffu + ((x.u >> 16) & 1u);
  return (unsigned short)(r >> 16);
}

__device__ __forceinline__ unsigned cvtpk(float lo, float hi) {  // 2 bf16 in 1 op
  unsigned r;
  asm("v_cvt_pk_bf16_f32 %0, %1, %2" : "=v"(r) : "v"(lo), "v"(hi));
  return r;
}

__device__ __forceinline__ unsigned short f2bf_cvt(float f) {
  unsigned r;
  asm("v_cvt_pk_bf16_f32 %0, %1, 0" : "=v"(r) : "v"(f));
  return (unsigned short)r;
}

__device__ __forceinline__ float fexp2(float x) {
#if __has_builtin(__builtin_amdgcn_exp2f)
  return __builtin_amdgcn_exp2f(x);
#else
  return exp2f(x);
#endif
}

// ---------------------------- fp32 -> bf16 convert -------------------------
struct CvtArgs {
  const float* src[7];
  unsigned short* dst[7];
};

__global__ __launch_bounds__(256) void cvt_kernel(CvtArgs a) {
  const int bid = blockIdx.x;
  int t, i;
  if (bid < 24576) { t = bid >> 13; i = ((bid & 8191) << 8) + threadIdx.x; }
  else { const int r = bid - 24576; t = 3 + (r >> 10); i = ((r & 1023) << 8) + threadIdx.x; }
  const float4 v = ((const float4*)a.src[t])[i];
  ushort4 o;
  o.x = f2bf(v.x); o.y = f2bf(v.y); o.z = f2bf(v.z); o.w = f2bf(v.w);
  ((ushort4*)a.dst[t])[i] = o;
}

__global__ __launch_bounds__(256) void mask_kernel(const int* __restrict__ m,
                                                   float* __restrict__ mf) {
  const int i = blockIdx.x * 256 + threadIdx.x;  // 8192 total
  mf[i] = m[i] ? 0.0f : -65504.0f;
}

// ------------------------------- GEMM (NT) ---------------------------------
// out[m][n] = sum_k A[m][k]*W[n][k] + bias[n];  M=8192, N=K=1024
// 128x128 tile, BK=32; XCD chunks iterate n fastest (A-panel locality in L2).
struct GemmB {
  const unsigned short* A[3];
  const unsigned short* W[3];
  const float* bias[3];
  unsigned short* out[3];
};

template <int NB, int F32OUT>
__global__ __launch_bounds__(256, 2) void gemm_nt(GemmB gb, float* fout) {
  constexpr int K = 1024, N = 1024;
  __shared__ unsigned short As[128 * 32];
  __shared__ unsigned short Bs[128 * 32];

  const int nwg = NB * 512;
  const int wg = blockIdx.x;
  const int swz = (wg & 7) * (nwg >> 3) + (wg >> 3);  // XCD-bijective (nwg%8==0)
  const int which = swz >> 9;
  const int rr = swz & 511;
  const int m0 = (rr >> 3) * 128, n0 = (rr & 7) * 128;  // n fastest within chunk

  const unsigned short* __restrict__ A = gb.A[which];
  const unsigned short* __restrict__ W = gb.W[which];
  const float* __restrict__ bias = gb.bias[which];

  const int tid = threadIdx.x;
  const int w = tid >> 6, l = tid & 63;
  const int wm = (w >> 1) * 64, wn = (w & 1) * 64;
  const int fr = l & 15, kg = (l >> 4) * 8;

  const int srow = w * 32 + (l >> 2);
  const int sk = (l & 3) * 8;
  const unsigned short* Ag0 = A + (size_t)(m0 + srow) * K + sk;
  const unsigned short* Ag1 = Ag0 + (size_t)16 * K;
  const unsigned short* Wg0 = W + (size_t)(n0 + srow) * K + sk;
  const unsigned short* Wg1 = Wg0 + (size_t)16 * K;
  unsigned short* Asl0 = As + w * 1024;
  unsigned short* Asl1 = As + w * 1024 + 512;
  unsigned short* Bsl0 = Bs + w * 1024;
  unsigned short* Bsl1 = Bs + w * 1024 + 512;

  f32x4 acc[4][4] = {};

  for (int kt = 0; kt < K; kt += 32) {
    gload_lds16(Ag0 + kt, Asl0);
    gload_lds16(Ag1 + kt, Asl1);
    gload_lds16(Wg0 + kt, Bsl0);
    gload_lds16(Wg1 + kt, Bsl1);
    __syncthreads();

    bf16x8 af[4], bfv[4];
#pragma unroll
    for (int mt = 0; mt < 4; ++mt)
      af[mt] = *(const bf16x8*)(As + (wm + mt * 16 + fr) * 32 + kg);
#pragma unroll
    for (int nt = 0; nt < 4; ++nt)
      bfv[nt] = *(const bf16x8*)(Bs + (wn + nt * 16 + fr) * 32 + kg);
#pragma unroll
    for (int mt = 0; mt < 4; ++mt)
#pragma unroll
      for (int nt = 0; nt < 4; ++nt)
        acc[mt][nt] = MFMA16(af[mt], bfv[nt], acc[mt][nt]);
    __syncthreads();
  }

  const int rg = (l >> 4) * 4;
  float bv[4];
#pragma unroll
  for (int nt = 0; nt < 4; ++nt) bv[nt] = bias[n0 + wn + nt * 16 + fr];

#pragma unroll
  for (int mt = 0; mt < 4; ++mt) {
#pragma unroll
    for (int nt = 0; nt < 4; ++nt) {
      const int col = n0 + wn + nt * 16 + fr;
#pragma unroll
      for (int r = 0; r < 4; ++r) {
        const size_t row = (size_t)(m0 + wm + mt * 16 + rg + r);
        const float vv = acc[mt][nt][r] + bv[nt];
        if (F32OUT) fout[row * N + col] = vv;
        else        gb.out[which][row * N + col] = f2bf(vv);
      }
    }
  }
}

// ----------------------------- flash attention -----------------------------
// Swapped QK^T: S^T = K·Q^T via mfma_32x32x16; lane owns q-col (l&31).
// P stays in registers (cvt_pk); V B-frags read at P's natural kv-permutation.
// grid: 1024 blocks (16 qtile x 16 h x 4 b); 4 waves x 32 q-rows; KVBLK=64.
__global__ __launch_bounds__(256, 3) void attn_kernel(
    const unsigned short* __restrict__ QP,
    const unsigned short* __restrict__ KP,
    const unsigned short* __restrict__ VP,
    const float* __restrict__ maskf,        // [B][T] additive (0 / -65504)
    unsigned short* __restrict__ O)
{
  __shared__ unsigned short Kls[64 * 64];   // [kv][d], 16B-slot XOR swizzle
  __shared__ unsigned short VTls[64 * 64];  // [d][kv], 16B-slot XOR swizzle
  __shared__ float wscr[4][32];             // per-wave alpha / 1/l scratch

  const int wg = blockIdx.x;
  const int swz = (wg & 7) * 128 + (wg >> 3);
  const int qt = swz & 15, h = (swz >> 4) & 15, b = swz >> 8;

  const int tid = threadIdx.x, w = tid >> 6, l = tid & 63;
  const int lq = l & 31, hi = l >> 5, hi8 = hi * 8;
  const size_t brow = (size_t)b * 2048;
  const int hcol = h * 64;
  const int q0 = qt * 128 + w * 32;

  // ---- Q B-frags (hoisted): qf[s] = Q[q0+lq][16s + hi8 .. +8] ----
  bf16x8 qf[4];
  {
    const unsigned short* qp = QP + (brow + q0 + lq) * 1024 + hcol + hi8;
    qf[0] = *(const bf16x8*)(qp);
    qf[1] = *(const bf16x8*)(qp + 16);
    qf[2] = *(const bf16x8*)(qp + 32);
    qf[3] = *(const bf16x8*)(qp + 48);
  }

  // K staging via global_load_lds, pre-swizzled source (m173 pattern):
  // dest byte (w*2+r)*1024 + l*16 -> kv = w*16+r*8+(l>>3), slot = l&7;
  // source col-chunk = 8*((l&7) ^ (kv&7)), kv&7 == l>>3.
  const int skv = l >> 3;
  const int schunk = 8 * ((l & 7) ^ skv);
  const unsigned short* Ksrc0 = KP + (brow + w * 16 + skv) * 1024 + hcol + schunk;
  const unsigned short* Ksrc1 = Ksrc0 + (size_t)8 * 1024;
  unsigned short* Kdst0 = Kls + (w * 2 + 0) * 512;
  unsigned short* Kdst1 = Kls + (w * 2 + 1) * 512;

  // V^T staging (4x4 micro-transpose): wave w writes VT rows w*16..+15
  const int tkv = (l & 15) * 4;
  const int td = w * 16 + (l >> 4) * 4;
  const unsigned short* Vsrc = VP + (brow + tkv) * 1024 + hcol + td;

  float m_run = -3e38f, l_run = 0.f;
  f32x16 ob0 = {}, ob1 = {};
  const float cs = 0.04508422823f;  // log2(e)/32  (scale folded into exp2)
  const float* mrow = maskf + (size_t)b * 2048;
  const int dsw = (lq & 7) << 4;
  const char* vtb0 = (const char*)VTls + (size_t)lq * 128;
  const char* vtb1 = (const char*)VTls + (size_t)(32 + lq) * 128;
  const char* klb0 = (const char*)Kls + (size_t)lq * 128;
  const char* klb1 = (const char*)Kls + (size_t)(32 + lq) * 128;

  for (int kv0 = 0; kv0 < 2048; kv0 += 64) {
    __syncthreads();  // prior tile's LDS reads complete
    gload_lds16(Ksrc0 + (size_t)kv0 * 1024, Kdst0);
    gload_lds16(Ksrc1 + (size_t)kv0 * 1024, Kdst1);
    {
      const unsigned short* vs = Vsrc + (size_t)kv0 * 1024;
      ushort4 r0 = *(const ushort4*)(vs);
      ushort4 r1 = *(const ushort4*)(vs + 1024);
      ushort4 r2 = *(const ushort4*)(vs + 2048);
      ushort4 r3 = *(const ushort4*)(vs + 3072);
      ushort4 c0 = {r0.x, r1.x, r2.x, r3.x};
      ushort4 c1 = {r0.y, r1.y, r2.y, r3.y};
      ushort4 c2 = {r0.z, r1.z, r2.z, r3.z};
      ushort4 c3 = {r0.w, r1.w, r2.w, r3.w};
      char* vb = (char*)VTls;
      *(ushort4*)(vb + (td + 0) * 128 + ((tkv * 2) ^ (((td + 0) & 7) << 4))) = c0;
      *(ushort4*)(vb + (td + 1) * 128 + ((tkv * 2) ^ (((td + 1) & 7) << 4))) = c1;
      *(ushort4*)(vb + (td + 2) * 128 + ((tkv * 2) ^ (((td + 2) & 7) << 4))) = c2;
      *(ushort4*)(vb + (td + 3) * 128 + ((tkv * 2) ^ (((td + 3) & 7) << 4))) = c3;
    }
    __syncthreads();

    // ---- S^T = K · Q^T : C rows = kv, cols = q ----
    f32x16 s0 = {}, s1 = {};
#pragma unroll
    for (int s = 0; s < 4; ++s) {
      const int co = (s * 32 + hi * 16) ^ dsw;
      bf16x8 k0 = *(const bf16x8*)(klb0 + co);
      bf16x8 k1 = *(const bf16x8*)(klb1 + co);
      s0 = MFMA32(k0, qf[s], s0);
      s1 = MFMA32(k1, qf[s], s1);
    }

    // ---- mask (fast-path skip; additive, pre-scale domain: x32) ----
    const float mfv = mrow[kv0 + l];
    if (__any(mfv != 0.0f)) {
#pragma unroll
      for (int r = 0; r < 16; ++r) {
        const int kvr = (r & 3) + 8 * (r >> 2) + 4 * hi;
        s0[r] += 32.0f * mrow[kv0 + kvr];
        s1[r] += 32.0f * mrow[kv0 + 32 + kvr];
      }
    }

    // ---- row max (in-register tree + one cross-half shfl) ----
    float t0[8];
#pragma unroll
    for (int r = 0; r < 8; ++r) t0[r] = fmaxf(s0[r], s0[r + 8]);
#pragma unroll
    for (int r = 0; r < 8; ++r) t0[r] = fmaxf(t0[r], fmaxf(s1[r], s1[r + 8]));
#pragma unroll
    for (int r = 0; r < 4; ++r) t0[r] = fmaxf(t0[r], t0[r + 4]);
    float mx = fmaxf(fmaxf(t0[0], t0[1]), fmaxf(t0[2], t0[3]));
    mx = fmaxf(mx, __shfl_xor(mx, 32));

    // ---- defer-max rescale (raw-score threshold 256 = 8/scale) ----
    if (!__all(mx - m_run <= 256.0f)) {
      const float mn = fmaxf(m_run, mx);
      const float alpha = fexp2((m_run - mn) * cs);
      if (l < 32) wscr[w][lq] = alpha;
      m_run = mn;
      l_run *= alpha;
#pragma unroll
      for (int g = 0; g < 4; ++g) {
        const f32x4 av = *(const f32x4*)&wscr[w][g * 8 + hi * 4];
#pragma unroll
        for (int c = 0; c < 4; ++c) {
          ob0[g * 4 + c] *= av[c];
          ob1[g * 4 + c] *= av[c];
        }
      }
    }

    // ---- exp2 + row sum ----
    const float m2 = m_run * cs;
    float ps0 = 0.f, ps1 = 0.f, ps2 = 0.f, ps3 = 0.f;
#pragma unroll
    for (int r = 0; r < 16; r += 4) {
      s0[r + 0] = fexp2(fmaf(s0[r + 0], cs, -m2)); ps0 += s0[r + 0];
      s0[r + 1] = fexp2(fmaf(s0[r + 1], cs, -m2)); ps1 += s0[r + 1];
      s0[r + 2] = fexp2(fmaf(s0[r + 2], cs, -m2)); ps2 += s0[r + 2];
      s0[r + 3] = fexp2(fmaf(s0[r + 3], cs, -m2)); ps3 += s0[r + 3];
    }
#pragma unroll
    for (int r = 0; r < 16; r += 4) {
      s1[r + 0] = fexp2(fmaf(s1[r + 0], cs, -m2)); ps0 += s1[r + 0];
      s1[r + 1] = fexp2(fmaf(s1[r + 1], cs, -m2)); ps1 += s1[r + 1];
      s1[r + 2] = fexp2(fmaf(s1[r + 2], cs, -m2)); ps2 += s1[r + 2];
      s1[r + 3] = fexp2(fmaf(s1[r + 3], cs, -m2)); ps3 += s1[r + 3];
    }
    float ps = (ps0 + ps1) + (ps2 + ps3);
    l_run += ps + __shfl_xor(ps, 32);

    // ---- PV: A-frag = own P regs (cvt_pk); B-frag = V at matching kv perm.
    // slot j of step t: kv = 32*bk + (j&3) + 8*((j>>2)+2t) + 4*hi
    // -> V chunks at colbyte (64bk+32t+8hi) and (+16), XOR dsw.
#define PV_BLOCK(SP, BK)                                                     \
  {                                                                          \
    _Pragma("unroll")                                                        \
    for (int t = 0; t < 2; ++t) {                                            \
      uint4v pw;                                                             \
      pw[0] = cvtpk(SP[8 * t + 0], SP[8 * t + 1]);                           \
      pw[1] = cvtpk(SP[8 * t + 2], SP[8 * t + 3]);                           \
      pw[2] = cvtpk(SP[8 * t + 4], SP[8 * t + 5]);                           \
      pw[3] = cvtpk(SP[8 * t + 6], SP[8 * t + 7]);                           \
      const bf16x8 pa = __builtin_bit_cast(bf16x8, pw);                      \
      const int cA = ((BK) * 64 + t * 32 + hi8) ^ dsw;                       \
      const int cB = ((BK) * 64 + t * 32 + 16 + hi8) ^ dsw;                  \
      const bf16x4 va0 = *(const bf16x4*)(vtb0 + cA);                        \
      const bf16x4 vb0v = *(const bf16x4*)(vtb0 + cB);                       \
      const bf16x4 va1 = *(const bf16x4*)(vtb1 + cA);                        \
      const bf16x4 vb1v = *(const bf16x4*)(vtb1 + cB);                       \
      const bf16x8 v0 = {va0[0], va0[1], va0[2], va0[3],                     \
                         vb0v[0], vb0v[1], vb0v[2], vb0v[3]};                \
      const bf16x8 v1 = {va1[0], va1[1], va1[2], va1[3],                     \
                         vb1v[0], vb1v[1], vb1v[2], vb1v[3]};                \
      ob0 = MFMA32(pa, v0, ob0);                                             \
      ob1 = MFMA32(pa, v1, ob1);                                             \
    }                                                                        \
  }
    PV_BLOCK(s0, 0)
    PV_BLOCK(s1, 1)
#undef PV_BLOCK
  }

  // ---- epilogue: O * (1/l) -> bf16 ----
  if (l < 32) wscr[w][lq] = 1.0f / l_run;
#pragma unroll
  for (int g = 0; g < 4; ++g) {
    const f32x4 iv = *(const f32x4*)&wscr[w][g * 8 + hi * 4];
#pragma unroll
    for (int c = 0; c < 4; ++c) {
      const int qr = g * 8 + hi * 4 + c;
      const size_t row = brow + (size_t)(q0 + qr);
      O[row * 1024 + hcol + lq]      = f2bf_cvt(ob0[g * 4 + c] * iv[c]);
      O[row * 1024 + hcol + 32 + lq] = f2bf_cvt(ob1[g * 4 + c] * iv[c]);
    }
  }
}

// ------------------------------ launch -------------------------------------
extern "C" void kernel_launch(void* const* d_in, const int* in_sizes, int n_in,
                              void* d_out, int out_size, void* d_ws, size_t ws_size,
                              hipStream_t stream) {
  const float* q  = (const float*)d_in[0];
  const float* k  = (const float*)d_in[1];
  const float* v  = (const float*)d_in[2];
  const int*  msk = (const int*)d_in[3];
  const float* Wq = (const float*)d_in[4];
  const float* bq = (const float*)d_in[5];
  const float* Wk = (const float*)d_in[6];
  const float* bk = (const float*)d_in[7];
  const float* Wv = (const float*)d_in[8];
  const float* bv = (const float*)d_in[9];
  const float* Wo = (const float*)d_in[10];
  const float* bo = (const float*)d_in[11];

  char* ws = (char*)d_ws;
  const size_t SZ_BT = (size_t)8192 * 1024 * 2;  // 16 MiB
  const size_t SZ_W  = (size_t)1024 * 1024 * 2;  // 2 MiB
  unsigned short* qb  = (unsigned short*)(ws);
  unsigned short* kb  = (unsigned short*)(ws + SZ_BT);
  unsigned short* vb  = (unsigned short*)(ws + 2 * SZ_BT);
  unsigned short* Wqb = (unsigned short*)(ws + 3 * SZ_BT);
  unsigned short* Wkb = (unsigned short*)(ws + 3 * SZ_BT + SZ_W);
  unsigned short* Wvb = (unsigned short*)(ws + 3 * SZ_BT + 2 * SZ_W);
  unsigned short* Wob = (unsigned short*)(ws + 3 * SZ_BT + 3 * SZ_W);
  unsigned short* QPp = (unsigned short*)(ws + 3 * SZ_BT + 4 * SZ_W);
  unsigned short* KPp = (unsigned short*)(ws + 4 * SZ_BT + 4 * SZ_W);
  unsigned short* VPp = (unsigned short*)(ws + 5 * SZ_BT + 4 * SZ_W);
  unsigned short* AOp = (unsigned short*)(ws + 6 * SZ_BT + 4 * SZ_W);
  float*          mkf = (float*)(ws + 7 * SZ_BT + 4 * SZ_W);

  CvtArgs ca;
  ca.src[0] = q;  ca.dst[0] = qb;
  ca.src[1] = k;  ca.dst[1] = kb;
  ca.src[2] = v;  ca.dst[2] = vb;
  ca.src[3] = Wq; ca.dst[3] = Wqb;
  ca.src[4] = Wk; ca.dst[4] = Wkb;
  ca.src[5] = Wv; ca.dst[5] = Wvb;
  ca.src[6] = Wo; ca.dst[6] = Wob;
  cvt_kernel<<<dim3(28672), 256, 0, stream>>>(ca);
  mask_kernel<<<dim3(32), 256, 0, stream>>>(msk, mkf);

  GemmB g3;
  g3.A[0] = qb; g3.W[0] = Wqb; g3.bias[0] = bq; g3.out[0] = QPp;
  g3.A[1] = kb; g3.W[1] = Wkb; g3.bias[1] = bk; g3.out[1] = KPp;
  g3.A[2] = vb; g3.W[2] = Wvb; g3.bias[2] = bv; g3.out[2] = VPp;
  gemm_nt<3, 0><<<dim3(1536), 256, 0, stream>>>(g3, nullptr);

  attn_kernel<<<dim3(1024), 256, 0, stream>>>(QPp, KPp, VPp, mkf, AOp);

  GemmB g1;
  g1.A[0] = AOp; g1.W[0] = Wob; g1.bias[0] = bo; g1.out[0] = nullptr;
  gemm_nt<1, 1><<<dim3(512), 256, 0, stream>>>(g1, (float*)d_out);
}

// Round 4
// 382.105 us; speedup vs baseline: 1.3222x; 1.0597x over previous
//
#include <hip/hip_runtime.h>
#include <cstdint>
#include <cstddef>

// ---------------------------------------------------------------------------
// MultiHeadAttn: B=4, T=2048, D=1024, H=16, HD=64
// cvt(fp32->bf16) + maskf -> fused QKV GEMM (bf16, dbuf prefetch) ->
// flash attn (swapped QK^T, in-reg softmax, dbuf prefetch) -> out GEMM (fp32)
// ---------------------------------------------------------------------------

typedef __attribute__((ext_vector_type(8))) short bf16x8;
typedef __attribute__((ext_vector_type(4))) short bf16x4;
typedef __attribute__((ext_vector_type(4))) float f32x4;
typedef __attribute__((ext_vector_type(16))) float f32x16;
typedef __attribute__((ext_vector_type(4))) unsigned uint4v;

#define MFMA16(a, b, c) __builtin_amdgcn_mfma_f32_16x16x32_bf16((a), (b), (c), 0, 0, 0)
#define MFMA32(a, b, c) __builtin_amdgcn_mfma_f32_32x32x16_bf16((a), (b), (c), 0, 0, 0)

__device__ __forceinline__ void gload_lds16(const void* g, void* l) {
  __builtin_amdgcn_global_load_lds((const __attribute__((address_space(1))) void*)g,
                                   (__attribute__((address_space(3))) void*)l,
                                   16, 0, 0);
}

__device__ __forceinline__ unsigned short f2bf(float f) {  // RTNE
  union { float f; unsigned u; } x; x.f = f;
  unsigned r = x.u + 0x7fffu + ((x.u >> 16) & 1u);
  return (unsigned short)(r >> 16);
}

__device__ __forceinline__ unsigned cvtpk(float lo, float hi) {  // 2 bf16, 1 op
  unsigned r;
  asm("v_cvt_pk_bf16_f32 %0, %1, %2" : "=v"(r) : "v"(lo), "v"(hi));
  return r;
}

__device__ __forceinline__ unsigned short f2bf_cvt(float f) {
  unsigned r;
  asm("v_cvt_pk_bf16_f32 %0, %1, 0" : "=v"(r) : "v"(f));
  return (unsigned short)r;
}

__device__ __forceinline__ float fexp2(float x) {
#if __has_builtin(__builtin_amdgcn_exp2f)
  return __builtin_amdgcn_exp2f(x);
#else
  return exp2f(x);
#endif
}

// ---------------------------- fp32 -> bf16 convert -------------------------
struct CvtArgs {
  const float* src[7];
  unsigned short* dst[7];
};

__global__ __launch_bounds__(256) void cvt_kernel(CvtArgs a) {
  const int bid = blockIdx.x;
  int t, i;
  if (bid < 24576) { t = bid >> 13; i = ((bid & 8191) << 8) + threadIdx.x; }
  else { const int r = bid - 24576; t = 3 + (r >> 10); i = ((r & 1023) << 8) + threadIdx.x; }
  const float4 v = ((const float4*)a.src[t])[i];
  ushort4 o;
  o.x = f2bf(v.x); o.y = f2bf(v.y); o.z = f2bf(v.z); o.w = f2bf(v.w);
  ((ushort4*)a.dst[t])[i] = o;
}

__global__ __launch_bounds__(256) void mask_kernel(const int* __restrict__ m,
                                                   float* __restrict__ mf) {
  const int i = blockIdx.x * 256 + threadIdx.x;  // 8192 total
  mf[i] = m[i] ? 0.0f : -65504.0f;
}

// ------------------------------- GEMM (NT) ---------------------------------
// out[m][n] = sum_k A[m][k]*W[n][k] + bias[n];  M=8192, N=K=1024
// 128x128 tile, BK=32, double-buffered prefetch, 1 barrier/K-step.
struct GemmB {
  const unsigned short* A[3];
  const unsigned short* W[3];
  const float* bias[3];
  unsigned short* out[3];
};

template <int NB, int F32OUT>
__global__ __launch_bounds__(256, 2) void gemm_nt(GemmB gb, float* fout) {
  constexpr int K = 1024, N = 1024;
  __shared__ unsigned short As[2][128 * 32];
  __shared__ unsigned short Bs[2][128 * 32];

  const int nwg = NB * 512;
  const int wg = blockIdx.x;
  const int swz = (wg & 7) * (nwg >> 3) + (wg >> 3);  // XCD-bijective (nwg%8==0)
  const int which = swz >> 9;
  const int rr = swz & 511;
  const int m0 = (rr >> 3) * 128, n0 = (rr & 7) * 128;  // n fastest in chunk

  const unsigned short* __restrict__ A = gb.A[which];
  const unsigned short* __restrict__ W = gb.W[which];
  const float* __restrict__ bias = gb.bias[which];

  const int tid = threadIdx.x;
  const int w = tid >> 6, l = tid & 63;
  const int wm = (w >> 1) * 64, wn = (w & 1) * 64;
  const int fr = l & 15, kg = (l >> 4) * 8;

  const int srow = w * 32 + (l >> 2);
  const int sk = (l & 3) * 8;
  const unsigned short* Ag0 = A + (size_t)(m0 + srow) * K + sk;
  const unsigned short* Ag1 = Ag0 + (size_t)16 * K;
  const unsigned short* Wg0 = W + (size_t)(n0 + srow) * K + sk;
  const unsigned short* Wg1 = Wg0 + (size_t)16 * K;
  const int sl0 = w * 1024, sl1 = w * 1024 + 512;

  // prologue: stage K-step 0 into buffer 0
  gload_lds16(Ag0, &As[0][sl0]);
  gload_lds16(Ag1, &As[0][sl1]);
  gload_lds16(Wg0, &Bs[0][sl0]);
  gload_lds16(Wg1, &Bs[0][sl1]);
  __syncthreads();

  f32x4 acc[4][4] = {};

  for (int kt = 0; kt < K; kt += 32) {
    const int cur = (kt >> 5) & 1, nxt = cur ^ 1;
    if (kt + 32 < K) {  // prefetch next K-step (latency hides under MFMA)
      gload_lds16(Ag0 + kt + 32, &As[nxt][sl0]);
      gload_lds16(Ag1 + kt + 32, &As[nxt][sl1]);
      gload_lds16(Wg0 + kt + 32, &Bs[nxt][sl0]);
      gload_lds16(Wg1 + kt + 32, &Bs[nxt][sl1]);
    }

    bf16x8 af[4], bfv[4];
#pragma unroll
    for (int mt = 0; mt < 4; ++mt)
      af[mt] = *(const bf16x8*)(&As[cur][(wm + mt * 16 + fr) * 32 + kg]);
#pragma unroll
    for (int nt = 0; nt < 4; ++nt)
      bfv[nt] = *(const bf16x8*)(&Bs[cur][(wn + nt * 16 + fr) * 32 + kg]);
#pragma unroll
    for (int mt = 0; mt < 4; ++mt)
#pragma unroll
      for (int nt = 0; nt < 4; ++nt)
        acc[mt][nt] = MFMA16(af[mt], bfv[nt], acc[mt][nt]);

    __syncthreads();  // drains vmcnt(0)+lgkmcnt(0): prefetch landed, reads done
  }

  const int rg = (l >> 4) * 4;
  float bv[4];
#pragma unroll
  for (int nt = 0; nt < 4; ++nt) bv[nt] = bias[n0 + wn + nt * 16 + fr];

#pragma unroll
  for (int mt = 0; mt < 4; ++mt) {
#pragma unroll
    for (int nt = 0; nt < 4; ++nt) {
      const int col = n0 + wn + nt * 16 + fr;
#pragma unroll
      for (int r = 0; r < 4; ++r) {
        const size_t row = (size_t)(m0 + wm + mt * 16 + rg + r);
        const float vv = acc[mt][nt][r] + bv[nt];
        if (F32OUT) fout[row * N + col] = vv;
        else        gb.out[which][row * N + col] = f2bf(vv);
      }
    }
  }
}

// ----------------------------- flash attention -----------------------------
// Swapped QK^T: S^T = K·Q^T via mfma_32x32x16; lane owns q-col (l&31).
// P stays in registers (cvt_pk); V B-frags read at P's natural kv-permutation.
// Double-buffered K/V tiles, prefetch-before-compute, 1 barrier/iter.
// grid: 1024 blocks (16 qtile x 16 h x 4 b); 4 waves x 32 q-rows; KVBLK=64.
__global__ __launch_bounds__(256, 3) void attn_kernel(
    const unsigned short* __restrict__ QP,
    const unsigned short* __restrict__ KP,
    const unsigned short* __restrict__ VP,
    const float* __restrict__ maskf,        // [B][T] additive (0 / -65504)
    unsigned short* __restrict__ O)
{
  __shared__ unsigned short Kls[2][64 * 64];   // [kv][d], 16B-slot XOR swizzle
  __shared__ unsigned short VTls[2][64 * 64];  // [d][kv], 16B-slot XOR swizzle
  __shared__ float wscr[4][32];                // per-wave alpha / 1/l scratch

  const int wg = blockIdx.x;
  const int swz = (wg & 7) * 128 + (wg >> 3);
  const int qt = swz & 15, h = (swz >> 4) & 15, b = swz >> 8;

  const int tid = threadIdx.x, w = tid >> 6, l = tid & 63;
  const int lq = l & 31, hi = l >> 5, hi8 = hi * 8;
  const size_t brow = (size_t)b * 2048;
  const int hcol = h * 64;
  const int q0 = qt * 128 + w * 32;

  // ---- Q B-frags (hoisted) ----
  bf16x8 qf[4];
  {
    const unsigned short* qp = QP + (brow + q0 + lq) * 1024 + hcol + hi8;
    qf[0] = *(const bf16x8*)(qp);
    qf[1] = *(const bf16x8*)(qp + 16);
    qf[2] = *(const bf16x8*)(qp + 32);
    qf[3] = *(const bf16x8*)(qp + 48);
  }

  // K staging via global_load_lds, pre-swizzled source (m173 pattern)
  const int skv = l >> 3;
  const int schunk = 8 * ((l & 7) ^ skv);
  const unsigned short* Ksrc0 = KP + (brow + w * 16 + skv) * 1024 + hcol + schunk;
  const unsigned short* Ksrc1 = Ksrc0 + (size_t)8 * 1024;
  const int kdst0 = (w * 2 + 0) * 512;
  const int kdst1 = (w * 2 + 1) * 512;

  // V^T staging (4x4 micro-transpose): wave w writes VT rows w*16..+15
  const int tkv = (l & 15) * 4;
  const int td = w * 16 + (l >> 4) * 4;
  const unsigned short* Vsrc = VP + (brow + tkv) * 1024 + hcol + td;
  const int vco0 = (td + 0) * 128 + ((tkv * 2) ^ (((td + 0) & 7) << 4));
  const int vco1 = (td + 1) * 128 + ((tkv * 2) ^ (((td + 1) & 7) << 4));
  const int vco2 = (td + 2) * 128 + ((tkv * 2) ^ (((td + 2) & 7) << 4));
  const int vco3 = (td + 3) * 128 + ((tkv * 2) ^ (((td + 3) & 7) << 4));

  // ---- prologue: stage tile 0 into buffer 0 ----
  gload_lds16(Ksrc0, &Kls[0][kdst0]);
  gload_lds16(Ksrc1, &Kls[0][kdst1]);
  {
    ushort4 r0 = *(const ushort4*)(Vsrc);
    ushort4 r1 = *(const ushort4*)(Vsrc + 1024);
    ushort4 r2 = *(const ushort4*)(Vsrc + 2048);
    ushort4 r3 = *(const ushort4*)(Vsrc + 3072);
    char* vb = (char*)&VTls[0][0];
    ushort4 c0 = {r0.x, r1.x, r2.x, r3.x};
    ushort4 c1 = {r0.y, r1.y, r2.y, r3.y};
    ushort4 c2 = {r0.z, r1.z, r2.z, r3.z};
    ushort4 c3 = {r0.w, r1.w, r2.w, r3.w};
    *(ushort4*)(vb + vco0) = c0;
    *(ushort4*)(vb + vco1) = c1;
    *(ushort4*)(vb + vco2) = c2;
    *(ushort4*)(vb + vco3) = c3;
  }
  __syncthreads();

  float m_run = -3e38f, l_run = 0.f;
  f32x16 ob0 = {}, ob1 = {};
  const float cs = 0.04508422823f;  // log2(e)/32  (scale folded into exp2)
  const float* mrow = maskf + (size_t)b * 2048;
  const int dsw = (lq & 7) << 4;
  const size_t rb0 = (size_t)lq * 128;
  const size_t rb1 = (size_t)(32 + lq) * 128;

  for (int it = 0; it < 32; ++it) {
    const int cur = it & 1, nxt = cur ^ 1;
    const int kv0 = it * 64;

    // ---- prefetch tile it+1 (async; latency hides under compute) ----
    ushort4 pr0, pr1, pr2, pr3;
    if (it < 31) {
      const size_t koff = (size_t)(kv0 + 64) * 1024;
      gload_lds16(Ksrc0 + koff, &Kls[nxt][kdst0]);
      gload_lds16(Ksrc1 + koff, &Kls[nxt][kdst1]);
      const unsigned short* vs = Vsrc + koff;
      pr0 = *(const ushort4*)(vs);
      pr1 = *(const ushort4*)(vs + 1024);
      pr2 = *(const ushort4*)(vs + 2048);
      pr3 = *(const ushort4*)(vs + 3072);
    }

    const char* klb0 = (const char*)&Kls[cur][0] + rb0;
    const char* klb1 = (const char*)&Kls[cur][0] + rb1;
    const char* vtb0 = (const char*)&VTls[cur][0] + rb0;
    const char* vtb1 = (const char*)&VTls[cur][0] + rb1;

    // ---- S^T = K · Q^T ----
    f32x16 s0 = {}, s1 = {};
#pragma unroll
    for (int s = 0; s < 4; ++s) {
      const int co = (s * 32 + hi * 16) ^ dsw;
      bf16x8 k0 = *(const bf16x8*)(klb0 + co);
      bf16x8 k1 = *(const bf16x8*)(klb1 + co);
      s0 = MFMA32(k0, qf[s], s0);
      s1 = MFMA32(k1, qf[s], s1);
    }

    // ---- mask (fast-path skip; additive, pre-scale domain: x32) ----
    const float mfv = mrow[kv0 + l];
    if (__any(mfv != 0.0f)) {
#pragma unroll
      for (int r = 0; r < 16; ++r) {
        const int kvr = (r & 3) + 8 * (r >> 2) + 4 * hi;
        s0[r] += 32.0f * mrow[kv0 + kvr];
        s1[r] += 32.0f * mrow[kv0 + 32 + kvr];
      }
    }

    // ---- row max (in-register tree + one cross-half shfl) ----
    float t0[8];
#pragma unroll
    for (int r = 0; r < 8; ++r) t0[r] = fmaxf(s0[r], s0[r + 8]);
#pragma unroll
    for (int r = 0; r < 8; ++r) t0[r] = fmaxf(t0[r], fmaxf(s1[r], s1[r + 8]));
#pragma unroll
    for (int r = 0; r < 4; ++r) t0[r] = fmaxf(t0[r], t0[r + 4]);
    float mx = fmaxf(fmaxf(t0[0], t0[1]), fmaxf(t0[2], t0[3]));
    mx = fmaxf(mx, __shfl_xor(mx, 32));

    // ---- defer-max rescale (raw-score threshold 256 = 8/scale) ----
    if (!__all(mx - m_run <= 256.0f)) {
      const float mn = fmaxf(m_run, mx);
      const float alpha = fexp2((m_run - mn) * cs);
      if (l < 32) wscr[w][lq] = alpha;
      m_run = mn;
      l_run *= alpha;
#pragma unroll
      for (int g = 0; g < 4; ++g) {
        const f32x4 av = *(const f32x4*)&wscr[w][g * 8 + hi * 4];
#pragma unroll
        for (int c = 0; c < 4; ++c) {
          ob0[g * 4 + c] *= av[c];
          ob1[g * 4 + c] *= av[c];
        }
      }
    }

    // ---- exp2 + row sum ----
    const float m2 = m_run * cs;
    float ps0 = 0.f, ps1 = 0.f, ps2 = 0.f, ps3 = 0.f;
#pragma unroll
    for (int r = 0; r < 16; r += 4) {
      s0[r + 0] = fexp2(fmaf(s0[r + 0], cs, -m2)); ps0 += s0[r + 0];
      s0[r + 1] = fexp2(fmaf(s0[r + 1], cs, -m2)); ps1 += s0[r + 1];
      s0[r + 2] = fexp2(fmaf(s0[r + 2], cs, -m2)); ps2 += s0[r + 2];
      s0[r + 3] = fexp2(fmaf(s0[r + 3], cs, -m2)); ps3 += s0[r + 3];
    }
#pragma unroll
    for (int r = 0; r < 16; r += 4) {
      s1[r + 0] = fexp2(fmaf(s1[r + 0], cs, -m2)); ps0 += s1[r + 0];
      s1[r + 1] = fexp2(fmaf(s1[r + 1], cs, -m2)); ps1 += s1[r + 1];
      s1[r + 2] = fexp2(fmaf(s1[r + 2], cs, -m2)); ps2 += s1[r + 2];
      s1[r + 3] = fexp2(fmaf(s1[r + 3], cs, -m2)); ps3 += s1[r + 3];
    }
    float ps = (ps0 + ps1) + (ps2 + ps3);
    l_run += ps + __shfl_xor(ps, 32);

    // ---- PV: A-frag = own P regs (cvt_pk); B-frag = V at matching kv perm ----
#define PV_BLOCK(SP, BK)                                                     \
  {                                                                          \
    _Pragma("unroll")                                                        \
    for (int t = 0; t < 2; ++t) {                                            \
      uint4v pw;                                                             \
      pw[0] = cvtpk(SP[8 * t + 0], SP[8 * t + 1]);                           \
      pw[1] = cvtpk(SP[8 * t + 2], SP[8 * t + 3]);                           \
      pw[2] = cvtpk(SP[8 * t + 4], SP[8 * t + 5]);                           \
      pw[3] = cvtpk(SP[8 * t + 6], SP[8 * t + 7]);                           \
      const bf16x8 pa = __builtin_bit_cast(bf16x8, pw);                      \
      const int cA = ((BK) * 64 + t * 32 + hi8) ^ dsw;                       \
      const int cB = ((BK) * 64 + t * 32 + 16 + hi8) ^ dsw;                  \
      const bf16x4 va0 = *(const bf16x4*)(vtb0 + cA);                        \
      const bf16x4 vb0v = *(const bf16x4*)(vtb0 + cB);                       \
      const bf16x4 va1 = *(const bf16x4*)(vtb1 + cA);                        \
      const bf16x4 vb1v = *(const bf16x4*)(vtb1 + cB);                       \
      const bf16x8 v0 = {va0[0], va0[1], va0[2], va0[3],                     \
                         vb0v[0], vb0v[1], vb0v[2], vb0v[3]};                \
      const bf16x8 v1 = {va1[0], va1[1], va1[2], va1[3],                     \
                         vb1v[0], vb1v[1], vb1v[2], vb1v[3]};                \
      ob0 = MFMA32(pa, v0, ob0);                                             \
      ob1 = MFMA32(pa, v1, ob1);                                             \
    }                                                                        \
  }
    PV_BLOCK(s0, 0)
    PV_BLOCK(s1, 1)
#undef PV_BLOCK

    // ---- write prefetched V^T into next buffer (loads arrived by now) ----
    if (it < 31) {
      char* vb = (char*)&VTls[nxt][0];
      ushort4 c0 = {pr0.x, pr1.x, pr2.x, pr3.x};
      ushort4 c1 = {pr0.y, pr1.y, pr2.y, pr3.y};
      ushort4 c2 = {pr0.z, pr1.z, pr2.z, pr3.z};
      ushort4 c3 = {pr0.w, pr1.w, pr2.w, pr3.w};
      *(ushort4*)(vb + vco0) = c0;
      *(ushort4*)(vb + vco1) = c1;
      *(ushort4*)(vb + vco2) = c2;
      *(ushort4*)(vb + vco3) = c3;
    }

    __syncthreads();  // drains vmcnt(0)+lgkmcnt(0): K prefetch + VT writes done
  }

  // ---- epilogue: O * (1/l) -> bf16 ----
  if (l < 32) wscr[w][lq] = 1.0f / l_run;
#pragma unroll
  for (int g = 0; g < 4; ++g) {
    const f32x4 iv = *(const f32x4*)&wscr[w][g * 8 + hi * 4];
#pragma unroll
    for (int c = 0; c < 4; ++c) {
      const int qr = g * 8 + hi * 4 + c;
      const size_t row = brow + (size_t)(q0 + qr);
      O[row * 1024 + hcol + lq]      = f2bf_cvt(ob0[g * 4 + c] * iv[c]);
      O[row * 1024 + hcol + 32 + lq] = f2bf_cvt(ob1[g * 4 + c] * iv[c]);
    }
  }
}

// ------------------------------ launch -------------------------------------
extern "C" void kernel_launch(void* const* d_in, const int* in_sizes, int n_in,
                              void* d_out, int out_size, void* d_ws, size_t ws_size,
                              hipStream_t stream) {
  const float* q  = (const float*)d_in[0];
  const float* k  = (const float*)d_in[1];
  const float* v  = (const float*)d_in[2];
  const int*  msk = (const int*)d_in[3];
  const float* Wq = (const float*)d_in[4];
  const float* bq = (const float*)d_in[5];
  const float* Wk = (const float*)d_in[6];
  const float* bk = (const float*)d_in[7];
  const float* Wv = (const float*)d_in[8];
  const float* bv = (const float*)d_in[9];
  const float* Wo = (const float*)d_in[10];
  const float* bo = (const float*)d_in[11];

  char* ws = (char*)d_ws;
  const size_t SZ_BT = (size_t)8192 * 1024 * 2;  // 16 MiB
  const size_t SZ_W  = (size_t)1024 * 1024 * 2;  // 2 MiB
  unsigned short* qb  = (unsigned short*)(ws);
  unsigned short* kb  = (unsigned short*)(ws + SZ_BT);
  unsigned short* vb  = (unsigned short*)(ws + 2 * SZ_BT);
  unsigned short* Wqb = (unsigned short*)(ws + 3 * SZ_BT);
  unsigned short* Wkb = (unsigned short*)(ws + 3 * SZ_BT + SZ_W);
  unsigned short* Wvb = (unsigned short*)(ws + 3 * SZ_BT + 2 * SZ_W);
  unsigned short* Wob = (unsigned short*)(ws + 3 * SZ_BT + 3 * SZ_W);
  unsigned short* QPp = (unsigned short*)(ws + 3 * SZ_BT + 4 * SZ_W);
  unsigned short* KPp = (unsigned short*)(ws + 4 * SZ_BT + 4 * SZ_W);
  unsigned short* VPp = (unsigned short*)(ws + 5 * SZ_BT + 4 * SZ_W);
  unsigned short* AOp = (unsigned short*)(ws + 6 * SZ_BT + 4 * SZ_W);
  float*          mkf = (float*)(ws + 7 * SZ_BT + 4 * SZ_W);

  CvtArgs ca;
  ca.src[0] = q;  ca.dst[0] = qb;
  ca.src[1] = k;  ca.dst[1] = kb;
  ca.src[2] = v;  ca.dst[2] = vb;
  ca.src[3] = Wq; ca.dst[3] = Wqb;
  ca.src[4] = Wk; ca.dst[4] = Wkb;
  ca.src[5] = Wv; ca.dst[5] = Wvb;
  ca.src[6] = Wo; ca.dst[6] = Wob;
  cvt_kernel<<<dim3(28672), 256, 0, stream>>>(ca);
  mask_kernel<<<dim3(32), 256, 0, stream>>>(msk, mkf);

  GemmB g3;
  g3.A[0] = qb; g3.W[0] = Wqb; g3.bias[0] = bq; g3.out[0] = QPp;
  g3.A[1] = kb; g3.W[1] = Wkb; g3.bias[1] = bk; g3.out[1] = KPp;
  g3.A[2] = vb; g3.W[2] = Wvb; g3.bias[2] = bv; g3.out[2] = VPp;
  gemm_nt<3, 0><<<dim3(1536), 256, 0, stream>>>(g3, nullptr);

  attn_kernel<<<dim3(1024), 256, 0, stream>>>(QPp, KPp, VPp, mkf, AOp);

  GemmB g1;
  g1.A[0] = AOp; g1.W[0] = Wob; g1.bias[0] = bo; g1.out[0] = nullptr;
  gemm_nt<1, 1><<<dim3(512), 256, 0, stream>>>(g1, (float*)d_out);
}